// Round 4
// baseline (460.708 us; speedup 1.0000x reference)
//
#include <hip/hip_runtime.h>

// Problem dims
#define NN 128
#define MM 2048
#define EPSF 0.01f

typedef __bf16 bf16x8 __attribute__((ext_vector_type(8)));
typedef __bf16 bf16x4 __attribute__((ext_vector_type(4)));
typedef float  f32x4  __attribute__((ext_vector_type(4)));

// Workspace layout (float offsets), total 1442944 floats = 5.77 MB
#define WS_SLACK 0            // [n][m] fp32
#define WS_W2    262144       // [n][256] gz2*softplus(Wz2)
#define WS_GZ1   294912       // [n][256]
#define WS_YV    327680       // [n][8]  Y - gy2*Wy2
#define WS_CU2   328704       // [n]
#define WS_WTB   328832       // bf16 [256 k][256 z] = softplus(Wz1)
#define WS_A2    361600       // bf16 [2048 m][32] = [U | 1 | 0...]
#define WS_B2    394368       // bf16 [128 n][256 z][32] = [gy0*Wy0 | c0 | 0...]
#define WS_BX    918656       // bf16 [128 n][256 k][32] = [gy1*Wy1 | c1 | 0...]

__device__ __forceinline__ float softplusf(float x) {
    return x > 20.f ? x : log1pf(expf(x));
}

__device__ __forceinline__ float wave_red_sum(float v) {
#pragma unroll
    for (int off = 32; off; off >>= 1) v += __shfl_xor(v, off);
    return v;
}

// ---------------------------------------------------------------------------
// k_prep: WTB = bf16(softplus(Wz1)) [k][z]; A2 = [U | 1 | 0...]
// ---------------------------------------------------------------------------
__global__ __launch_bounds__(256) void k_prep(const float* __restrict__ Wz1,
                                              const float* __restrict__ U,
                                              float* __restrict__ ws) {
    int i = blockIdx.x * 256 + threadIdx.x;   // 131072 total
    if (i < 65536) {
        ((__bf16*)(ws + WS_WTB))[i] = (__bf16)softplusf(Wz1[i]);
    } else {
        int o = i - 65536;
        int m = o >> 5, cc = o & 31;
        float v = cc < 8 ? U[m * 8 + cc] : (cc == 8 ? 1.f : 0.f);
        ((__bf16*)(ws + WS_A2))[o] = (__bf16)v;
    }
}

// ---------------------------------------------------------------------------
// k_pern: context path, one block per n. Wave-per-output: coalesced weight-row
// load + 64-lane shuffle reduce (fixes the round-2 serial-row-walk latency).
// ---------------------------------------------------------------------------
__global__ __launch_bounds__(256) void k_pern(
    const float* __restrict__ X, const float* __restrict__ Y,
    const float* __restrict__ Wt0, const float* __restrict__ bt0,
    const float* __restrict__ Wt1, const float* __restrict__ bt1,
    const float* __restrict__ Wyu0, const float* __restrict__ byu0,
    const float* __restrict__ Wy0,
    const float* __restrict__ Wu0, const float* __restrict__ b0,
    const float* __restrict__ Wzu1, const float* __restrict__ bzu1,
    const float* __restrict__ Wyu1, const float* __restrict__ byu1,
    const float* __restrict__ Wy1,
    const float* __restrict__ Wu1, const float* __restrict__ b1,
    const float* __restrict__ Wzu2, const float* __restrict__ bzu2,
    const float* __restrict__ Wz2,
    const float* __restrict__ Wyu2, const float* __restrict__ byu2,
    const float* __restrict__ Wy2,
    const float* __restrict__ Wu2, const float* __restrict__ b2,
    float* __restrict__ ws)
{
    __shared__ float xs[64];
    __shared__ float u1s[256];
    __shared__ float u2s[256];
    __shared__ float c0s[256];
    __shared__ float c1s[256];
    __shared__ float gy0s[8], gy1s[8];
    const int n = blockIdx.x;
    const int t = threadIdx.x;
    const int w = t >> 6, lane = t & 63;

    if (t < 64) xs[t] = X[n * 64 + t];
    __syncthreads();

    // ---- phase 1: K=64 dots over X. outputs: u1[256], c0[256], gy0[8] ----
    const float xl = xs[lane];
    for (int o = w; o < 520; o += 4) {
        const float* row;
        if (o < 256)      row = Wt0 + o * 64;
        else if (o < 512) row = Wu0 + (o - 256) * 64;
        else              row = Wyu0 + (o - 512) * 64;
        float v = wave_red_sum(row[lane] * xl);
        if (lane == 0) {
            if (o < 256)      u1s[o] = fmaxf(v + bt0[o], 0.f);
            else if (o < 512) c0s[o - 256] = v + b0[o - 256];
            else              gy0s[o - 512] = v + byu0[o - 512];
        }
    }
    __syncthreads();

    // ---- phase 2: K=256 dots over u1. outputs: u2, gz1, c1, gy1 ----
    float4 uv1 = *(const float4*)&u1s[4 * lane];
    for (int o = w; o < 776; o += 4) {
        const float* row;
        if (o < 256)      row = Wt1 + o * 256;
        else if (o < 512) row = Wzu1 + (o - 256) * 256;
        else if (o < 768) row = Wu1 + (o - 512) * 256;
        else              row = Wyu1 + (o - 768) * 256;
        float4 wv = ((const float4*)row)[lane];
        float v = wave_red_sum(wv.x * uv1.x + wv.y * uv1.y + wv.z * uv1.z + wv.w * uv1.w);
        if (lane == 0) {
            if (o < 256)      u2s[o] = fmaxf(v + bt1[o], 0.f);
            else if (o < 512) ws[WS_GZ1 + n * 256 + (o - 256)] =
                                  fmaxf(v + bzu1[o - 256], 0.f);
            else if (o < 768) c1s[o - 512] = v + b1[o - 512];
            else              gy1s[o - 768] = v + byu1[o - 768];
        }
    }
    __syncthreads();

    // ---- phase 3: K=256 dots over u2. outputs: w2[256], yv[8], cu2[1] ----
    float4 uv2 = *(const float4*)&u2s[4 * lane];
    for (int o = w; o < 265; o += 4) {
        const float* row;
        if (o < 256)      row = Wzu2 + o * 256;
        else if (o < 264) row = Wyu2 + (o - 256) * 256;
        else              row = Wu2;
        float4 wv = ((const float4*)row)[lane];
        float v = wave_red_sum(wv.x * uv2.x + wv.y * uv2.y + wv.z * uv2.z + wv.w * uv2.w);
        if (lane == 0) {
            if (o < 256) {
                float gz2 = fmaxf(v + bzu2[o], 0.f);
                ws[WS_W2 + n * 256 + o] = gz2 * softplusf(Wz2[o]);
            } else if (o < 264) {
                int d = o - 256;
                float gy2 = v + byu2[d];
                ws[WS_YV + n * 8 + d] = Y[n * 8 + d] - gy2 * Wy2[d];
            } else {
                ws[WS_CU2 + n] = v + b2[0];
            }
        }
    }
    __syncthreads();

    // ---- phase 4: materialize B2/BX rows (bf16 [32] each) ----
    {
        __bf16* B2 = (__bf16*)(ws + WS_B2) + n * 8192 + t * 32;
        const float* wy = Wy0 + t * 8;
#pragma unroll
        for (int d = 0; d < 8; ++d) B2[d] = (__bf16)(gy0s[d] * wy[d]);
        B2[8] = (__bf16)c0s[t];
#pragma unroll
        for (int j = 9; j < 32; ++j) B2[j] = (__bf16)0.f;
    }
    {
        __bf16* Bx = (__bf16*)(ws + WS_BX) + n * 8192 + t * 32;
        const float* wy = Wy1 + t * 8;
#pragma unroll
        for (int d = 0; d < 8; ++d) Bx[d] = (__bf16)(gy1s[d] * wy[d]);
        Bx[8] = (__bf16)c1s[t];
#pragma unroll
        for (int j = 9; j < 32; ++j) Bx[j] = (__bf16)0.f;
    }
}

// ---------------------------------------------------------------------------
// k_main: round-2 structure (WTB via L2) + XOR-swizzled zh (kills the 8-way
// b128 read conflicts of the padded layout).
// ---------------------------------------------------------------------------
__device__ __forceinline__ int zh_off(int m, int ci) {   // ci = 16B-chunk idx
    return m * 256 + ((ci ^ (m & 7)) << 3);
}

__global__ __launch_bounds__(256, 3) void k_main(
    const float* __restrict__ U,
    float* __restrict__ ws)
{
    __shared__ __bf16 zh[64 * 256];   // 32 KB, XOR-swizzled
    __shared__ float gz1s[256];
    __shared__ float w2s[256];
    __shared__ float sdot[64];
    __shared__ float psum[4][64];

    const int t  = threadIdx.x;
    const int n  = blockIdx.y;
    const int m0 = blockIdx.x * 64;
    const int w    = t >> 6;
    const int lane = t & 63;
    const int c = lane & 15;
    const int q = lane >> 4;

    gz1s[t] = ws[WS_GZ1 + n * 256 + t];
    w2s[t]  = ws[WS_W2  + n * 256 + t];
    if (t < 64) {
        float sd = 0.f;
#pragma unroll
        for (int d = 0; d < 8; ++d)
            sd += U[(m0 + t) * 8 + d] * ws[WS_YV + n * 8 + d];
        sdot[t] = sd;
    }

    const __bf16* A2p = (const __bf16*)(ws + WS_A2);
    const __bf16* B2p = (const __bf16*)(ws + WS_B2) + n * 8192;
    const __bf16* BXp = (const __bf16*)(ws + WS_BX) + n * 8192;
    const __bf16* WTp = (const __bf16*)(ws + WS_WTB);

    // A2 fragments: rows m = m0 + c + 16mi
    bf16x8 a2f[4];
#pragma unroll
    for (int mi = 0; mi < 4; ++mi)
        a2f[mi] = *(const bf16x8*)(A2p + (m0 + 16 * mi + c) * 32 + q * 8);

    // ---- pre-GEMM: D1[z][m], wave w covers z in [64w, 64w+64) ----
    {
        bf16x8 b2f[4];
#pragma unroll
        for (int zt = 0; zt < 4; ++zt)
            b2f[zt] = *(const bf16x8*)(B2p + (64 * w + 16 * zt + c) * 32 + q * 8);
        f32x4 pre[4][4];
#pragma unroll
        for (int zt = 0; zt < 4; ++zt)
#pragma unroll
            for (int mi = 0; mi < 4; ++mi) {
                f32x4 zacc = {0.f, 0.f, 0.f, 0.f};
                pre[zt][mi] = __builtin_amdgcn_mfma_f32_16x16x32_bf16(
                    b2f[zt], a2f[mi], zacc, 0, 0, 0);
            }
#pragma unroll
        for (int zt = 0; zt < 4; ++zt) {
            const int zb = 64 * w + 16 * zt + 4 * q;
#pragma unroll
            for (int mi = 0; mi < 4; ++mi) {
                bf16x4 v4;
#pragma unroll
                for (int r = 0; r < 4; ++r)
                    v4[r] = (__bf16)(fmaxf(pre[zt][mi][r], 0.f) * gz1s[zb + r]);
                *(bf16x4*)&zh[zh_off(c + 16 * mi, zb >> 3) + (zb & 7)] = v4;
            }
        }
    }

    // ---- main GEMM: D2[m][k], wave w covers k in [64w, 64w+64) ----
    f32x4 acc[4][4];
#pragma unroll
    for (int mi = 0; mi < 4; ++mi)
#pragma unroll
        for (int kj = 0; kj < 4; ++kj)
            acc[mi][kj] = f32x4{0.f, 0.f, 0.f, 0.f};

    __syncthreads();

    for (int ch = 0; ch < 8; ++ch) {
        bf16x8 az[4], bw[4];
#pragma unroll
        for (int mi = 0; mi < 4; ++mi)
            az[mi] = *(const bf16x8*)&zh[zh_off(c + 16 * mi, ch * 4 + q)];
#pragma unroll
        for (int kj = 0; kj < 4; ++kj)
            bw[kj] = *(const bf16x8*)(WTp + (64 * w + 16 * kj + c) * 256 + ch * 32 + q * 8);
#pragma unroll
        for (int mi = 0; mi < 4; ++mi)
#pragma unroll
            for (int kj = 0; kj < 4; ++kj)
                acc[mi][kj] = __builtin_amdgcn_mfma_f32_16x16x32_bf16(
                    az[mi], bw[kj], acc[mi][kj], 0, 0, 0);
    }
    // rank-1 chunk: [U|1] x [gy1*Wy1 | c1]
    {
        bf16x8 bx[4];
#pragma unroll
        for (int kj = 0; kj < 4; ++kj)
            bx[kj] = *(const bf16x8*)(BXp + (64 * w + 16 * kj + c) * 32 + q * 8);
#pragma unroll
        for (int mi = 0; mi < 4; ++mi)
#pragma unroll
            for (int kj = 0; kj < 4; ++kj)
                acc[mi][kj] = __builtin_amdgcn_mfma_f32_16x16x32_bf16(
                    a2f[mi], bx[kj], acc[mi][kj], 0, 0, 0);
    }

    // ---- epilogue: p[m] = sum_k relu(acc)*w2[k] ----
    float p[4][4];
#pragma unroll
    for (int mi = 0; mi < 4; ++mi)
#pragma unroll
        for (int r = 0; r < 4; ++r) p[mi][r] = 0.f;
#pragma unroll
    for (int kj = 0; kj < 4; ++kj) {
        float w2v = w2s[64 * w + 16 * kj + c];
#pragma unroll
        for (int mi = 0; mi < 4; ++mi)
#pragma unroll
            for (int r = 0; r < 4; ++r)
                p[mi][r] += fmaxf(acc[mi][kj][r], 0.f) * w2v;
    }
#pragma unroll
    for (int mi = 0; mi < 4; ++mi)
#pragma unroll
        for (int r = 0; r < 4; ++r) {
            float v = p[mi][r];
            v += __shfl_xor(v, 8);
            v += __shfl_xor(v, 4);
            v += __shfl_xor(v, 2);
            v += __shfl_xor(v, 1);
            p[mi][r] = v;
        }
    if (c == 0) {
#pragma unroll
        for (int mi = 0; mi < 4; ++mi)
            *(float4*)&psum[w][16 * mi + 4 * q] =
                make_float4(p[mi][0], p[mi][1], p[mi][2], p[mi][3]);
    }
    __syncthreads();
    if (t < 64) {
        float cu2 = ws[WS_CU2 + n];
        float pp = psum[0][t] + psum[1][t] + psum[2][t] + psum[3][t];
        ws[WS_SLACK + n * 2048 + m0 + t] = sdot[t] - cu2 - pp;
    }
}

// ---------------------------------------------------------------------------
// k_lse: per-n stable logsumexp over m -> psi[n]
// ---------------------------------------------------------------------------
__global__ __launch_bounds__(256) void k_lse(const float* __restrict__ ws,
                                             float* __restrict__ out) {
    __shared__ float redmax[4];
    __shared__ float redsum[4];
    const int n = blockIdx.x;
    const int t = threadIdx.x;
    const float* s = ws + WS_SLACK + n * 2048;

    float vals[8];
    float mx = -3.4e38f;
#pragma unroll
    for (int i = 0; i < 8; ++i) {
        vals[i] = s[t + 256 * i];
        mx = fmaxf(mx, vals[i]);
    }
#pragma unroll
    for (int off = 32; off; off >>= 1) mx = fmaxf(mx, __shfl_xor(mx, off));
    if ((t & 63) == 0) redmax[t >> 6] = mx;
    __syncthreads();
    mx = fmaxf(fmaxf(redmax[0], redmax[1]), fmaxf(redmax[2], redmax[3]));

    float sum = 0.f;
#pragma unroll
    for (int i = 0; i < 8; ++i) sum += expf((vals[i] - mx) * (1.f / EPSF));
#pragma unroll
    for (int off = 32; off; off >>= 1) sum += __shfl_xor(sum, off);
    if ((t & 63) == 0) redsum[t >> 6] = sum;
    __syncthreads();
    if (t == 0) {
        float S = redsum[0] + redsum[1] + redsum[2] + redsum[3];
        out[n] = EPSF * logf(S * (1.f / 2048.f)) + mx;
    }
}

// ---------------------------------------------------------------------------
extern "C" void kernel_launch(void* const* d_in, const int* in_sizes, int n_in,
                              void* d_out, int out_size, void* d_ws, size_t ws_size,
                              hipStream_t stream) {
    const float* X    = (const float*)d_in[0];
    const float* Uu   = (const float*)d_in[1];
    const float* Yy   = (const float*)d_in[2];
    const float* Wt0  = (const float*)d_in[3];
    const float* bt0  = (const float*)d_in[4];
    const float* Wt1  = (const float*)d_in[5];
    const float* bt1  = (const float*)d_in[6];
    const float* Wyu0 = (const float*)d_in[7];
    const float* byu0 = (const float*)d_in[8];
    const float* Wy0  = (const float*)d_in[9];
    const float* Wu0  = (const float*)d_in[10];
    const float* b0   = (const float*)d_in[11];
    const float* Wzu1 = (const float*)d_in[12];
    const float* bzu1 = (const float*)d_in[13];
    const float* Wz1  = (const float*)d_in[14];
    const float* Wyu1 = (const float*)d_in[15];
    const float* byu1 = (const float*)d_in[16];
    const float* Wy1  = (const float*)d_in[17];
    const float* Wu1  = (const float*)d_in[18];
    const float* b1   = (const float*)d_in[19];
    const float* Wzu2 = (const float*)d_in[20];
    const float* bzu2 = (const float*)d_in[21];
    const float* Wz2  = (const float*)d_in[22];
    const float* Wyu2 = (const float*)d_in[23];
    const float* byu2 = (const float*)d_in[24];
    const float* Wy2  = (const float*)d_in[25];
    const float* Wu2  = (const float*)d_in[26];
    const float* b2   = (const float*)d_in[27];
    float* ws  = (float*)d_ws;
    float* out = (float*)d_out;

    k_prep<<<dim3(512), dim3(256), 0, stream>>>(Wz1, Uu, ws);
    k_pern<<<dim3(128), dim3(256), 0, stream>>>(
        X, Yy, Wt0, bt0, Wt1, bt1, Wyu0, byu0, Wy0, Wu0, b0,
        Wzu1, bzu1, Wyu1, byu1, Wy1, Wu1, b1,
        Wzu2, bzu2, Wz2, Wyu2, byu2, Wy2, Wu2, b2, ws);
    k_main<<<dim3(MM / 64, NN), dim3(256), 0, stream>>>(Uu, ws);
    k_lse<<<dim3(128), dim3(256), 0, stream>>>(ws, out);
}

// Round 5
// 238.002 us; speedup vs baseline: 1.9357x; 1.9357x over previous
//
#include <hip/hip_runtime.h>

// Problem dims
#define NN 128
#define MM 2048
#define EPSF 0.01f

typedef __bf16 bf16x8 __attribute__((ext_vector_type(8)));
typedef __bf16 bf16x4 __attribute__((ext_vector_type(4)));
typedef float  f32x4  __attribute__((ext_vector_type(4)));

// Workspace layout (float offsets), total 1442944 floats = 5.77 MB
#define WS_SLACK 0            // [n][m] fp32
#define WS_W2    262144       // [n][256] gz2*softplus(Wz2)
#define WS_GZ1   294912       // [n][256]
#define WS_YV    327680       // [n][8]  Y - gy2*Wy2
#define WS_CU2   328704       // [n]
#define WS_WTB   328832       // bf16 [256 k][256 z] = softplus(Wz1)
#define WS_A2    361600       // bf16 [2048 m][32] = [U | 1 | 0...]
#define WS_B2    394368       // bf16 [128 n][256 z][32] = [gy0*Wy0 | c0 | 0...]
#define WS_BX    918656       // bf16 [128 n][256 k][32] = [gy1*Wy1 | c1 | 0...]

__device__ __forceinline__ float softplusf(float x) {
    return x > 20.f ? x : log1pf(expf(x));
}

__device__ __forceinline__ bf16x8 ld_cvt8(const float* __restrict__ p) {
    const float4* p4 = (const float4*)p;
    float4 a = p4[0], b = p4[1];
    bf16x8 r;
    r[0] = (__bf16)a.x; r[1] = (__bf16)a.y; r[2] = (__bf16)a.z; r[3] = (__bf16)a.w;
    r[4] = (__bf16)b.x; r[5] = (__bf16)b.y; r[6] = (__bf16)b.z; r[7] = (__bf16)b.w;
    return r;
}

// ---------------------------------------------------------------------------
// k_prep: WTB = bf16(softplus(Wz1)) [k][z]; A2 = [U | 1 | 0...]
// ---------------------------------------------------------------------------
__global__ __launch_bounds__(256) void k_prep(const float* __restrict__ Wz1,
                                              const float* __restrict__ U,
                                              float* __restrict__ ws) {
    int i = blockIdx.x * 256 + threadIdx.x;   // 131072 total
    if (i < 65536) {
        ((__bf16*)(ws + WS_WTB))[i] = (__bf16)softplusf(Wz1[i]);
    } else {
        int o = i - 65536;
        int m = o >> 5, cc = o & 31;
        float v = cc < 8 ? U[m * 8 + cc] : (cc == 8 ? 1.f : 0.f);
        ((__bf16*)(ws + WS_A2))[o] = (__bf16)v;
    }
}

// ---------------------------------------------------------------------------
// k_ctx: whole context path, MFMA-batched over n. 8 blocks x 16 n-rows,
// 512 threads (8 waves). Levels are [16 x cols, K] GEMMs; waves stride over
// 16-col tiles. B-frags = weight rows (fp32 -> bf16 on load). Fuses the
// B2/BX materialization at the end.
// D = mfma(aF, bF): row(4q+r) = aF row (n-local), col(c) = bF row (out col).
// ---------------------------------------------------------------------------
__global__ __launch_bounds__(512) void k_ctx(
    const float* __restrict__ X, const float* __restrict__ Y,
    const float* __restrict__ Wt0, const float* __restrict__ bt0,
    const float* __restrict__ Wt1, const float* __restrict__ bt1,
    const float* __restrict__ Wyu0, const float* __restrict__ byu0,
    const float* __restrict__ Wy0,
    const float* __restrict__ Wu0, const float* __restrict__ b0,
    const float* __restrict__ Wzu1, const float* __restrict__ bzu1,
    const float* __restrict__ Wyu1, const float* __restrict__ byu1,
    const float* __restrict__ Wy1,
    const float* __restrict__ Wu1, const float* __restrict__ b1,
    const float* __restrict__ Wzu2, const float* __restrict__ bzu2,
    const float* __restrict__ Wz2,
    const float* __restrict__ Wyu2, const float* __restrict__ byu2,
    const float* __restrict__ Wy2,
    const float* __restrict__ Wu2, const float* __restrict__ b2,
    float* __restrict__ ws)
{
    __shared__ __bf16 u1b[16][264];   // A-frag layout, row stride 264 (16B-mult)
    __shared__ __bf16 u2b[16][264];
    __shared__ __bf16 c0b[16][256];
    __shared__ __bf16 c1b[16][256];
    __shared__ float gy0s[16][8];
    __shared__ float gy1s[16][8];

    const int t = threadIdx.x;
    const int w = t >> 6, lane = t & 63;
    const int c = lane & 15, q = lane >> 4;
    const int nb = blockIdx.x * 16;

    // ---- level 1: K=64 over X. 33 tiles: [0,16)=Wt0, [16,32)=Wu0, 32=Wyu0 ----
    bf16x8 a1[2];
#pragma unroll
    for (int ch = 0; ch < 2; ++ch)
        a1[ch] = ld_cvt8(X + (nb + c) * 64 + ch * 32 + q * 8);

    for (int tau = w; tau < 33; tau += 8) {
        const float* rp;
        if (tau < 16)      rp = Wt0 + (tau * 16 + c) * 64;
        else if (tau < 32) rp = Wu0 + ((tau - 16) * 16 + c) * 64;
        else               rp = Wyu0 + (c & 7) * 64;
        f32x4 D = {0.f, 0.f, 0.f, 0.f};
#pragma unroll
        for (int ch = 0; ch < 2; ++ch) {
            bf16x8 b = ld_cvt8(rp + ch * 32 + q * 8);
            D = __builtin_amdgcn_mfma_f32_16x16x32_bf16(a1[ch], b, D, 0, 0, 0);
        }
        if (tau < 16) {
            const int col = tau * 16 + c;
            const float bv = bt0[col];
#pragma unroll
            for (int r = 0; r < 4; ++r)
                u1b[4 * q + r][col] = (__bf16)fmaxf(D[r] + bv, 0.f);
        } else if (tau < 32) {
            const int col = (tau - 16) * 16 + c;
            const float bv = b0[col];
#pragma unroll
            for (int r = 0; r < 4; ++r)
                c0b[4 * q + r][col] = (__bf16)(D[r] + bv);
        } else if (c < 8) {
            const float bv = byu0[c];
#pragma unroll
            for (int r = 0; r < 4; ++r)
                gy0s[4 * q + r][c] = D[r] + bv;
        }
    }
    __syncthreads();

    // ---- level 2: K=256 over u1. 49 tiles: Wt1 | Wzu1 | Wu1 | Wyu1 ----
    bf16x8 a2[8];
#pragma unroll
    for (int ch = 0; ch < 8; ++ch)
        a2[ch] = *(const bf16x8*)&u1b[c][ch * 32 + q * 8];

    for (int tau = w; tau < 49; tau += 8) {
        const float* rp;
        if (tau < 16)      rp = Wt1 + (tau * 16 + c) * 256;
        else if (tau < 32) rp = Wzu1 + ((tau - 16) * 16 + c) * 256;
        else if (tau < 48) rp = Wu1 + ((tau - 32) * 16 + c) * 256;
        else               rp = Wyu1 + (c & 7) * 256;
        f32x4 D = {0.f, 0.f, 0.f, 0.f};
#pragma unroll
        for (int ch = 0; ch < 8; ++ch) {
            bf16x8 b = ld_cvt8(rp + ch * 32 + q * 8);
            D = __builtin_amdgcn_mfma_f32_16x16x32_bf16(a2[ch], b, D, 0, 0, 0);
        }
        if (tau < 16) {
            const int col = tau * 16 + c;
            const float bv = bt1[col];
#pragma unroll
            for (int r = 0; r < 4; ++r)
                u2b[4 * q + r][col] = (__bf16)fmaxf(D[r] + bv, 0.f);
        } else if (tau < 32) {
            const int col = (tau - 16) * 16 + c;
            const float bv = bzu1[col];
#pragma unroll
            for (int r = 0; r < 4; ++r)
                ws[WS_GZ1 + (nb + 4 * q + r) * 256 + col] = fmaxf(D[r] + bv, 0.f);
        } else if (tau < 48) {
            const int col = (tau - 32) * 16 + c;
            const float bv = b1[col];
#pragma unroll
            for (int r = 0; r < 4; ++r)
                c1b[4 * q + r][col] = (__bf16)(D[r] + bv);
        } else if (c < 8) {
            const float bv = byu1[c];
#pragma unroll
            for (int r = 0; r < 4; ++r)
                gy1s[4 * q + r][c] = D[r] + bv;
        }
    }
    __syncthreads();

    // ---- level 3: K=256 over u2. 17 tiles: Wzu2 | (Wyu2, Wu2) ----
    bf16x8 a3[8];
#pragma unroll
    for (int ch = 0; ch < 8; ++ch)
        a3[ch] = *(const bf16x8*)&u2b[c][ch * 32 + q * 8];

    for (int tau = w; tau < 17; tau += 8) {
        const float* rp;
        if (tau < 16) rp = Wzu2 + (tau * 16 + c) * 256;
        else          rp = (c < 8) ? (Wyu2 + c * 256) : Wu2;
        f32x4 D = {0.f, 0.f, 0.f, 0.f};
#pragma unroll
        for (int ch = 0; ch < 8; ++ch) {
            bf16x8 b = ld_cvt8(rp + ch * 32 + q * 8);
            D = __builtin_amdgcn_mfma_f32_16x16x32_bf16(a3[ch], b, D, 0, 0, 0);
        }
        if (tau < 16) {
            const int col = tau * 16 + c;
            const float bv = bzu2[col];
            const float sp = softplusf(Wz2[col]);
#pragma unroll
            for (int r = 0; r < 4; ++r) {
                float gz2 = fmaxf(D[r] + bv, 0.f);
                ws[WS_W2 + (nb + 4 * q + r) * 256 + col] = gz2 * sp;
            }
        } else if (c < 8) {
            const float bv = byu2[c];
            const float wy2 = Wy2[c];
#pragma unroll
            for (int r = 0; r < 4; ++r) {
                const int n = nb + 4 * q + r;
                ws[WS_YV + n * 8 + c] = Y[n * 8 + c] - (D[r] + bv) * wy2;
            }
        } else if (c == 8) {
#pragma unroll
            for (int r = 0; r < 4; ++r)
                ws[WS_CU2 + nb + 4 * q + r] = D[r] + b2[0];
        }
    }

    // ---- B2/BX materialization (inputs synced at the L2 barrier) ----
    {
        const int z = t & 255;
        const int which = t >> 8;   // 0 -> B2, 1 -> BX
        const float* wy = (which == 0 ? Wy0 : Wy1) + z * 8;
        float wv[8];
#pragma unroll
        for (int d = 0; d < 8; ++d) wv[d] = wy[d];
        __bf16* base = (__bf16*)(ws + (which == 0 ? WS_B2 : WS_BX));
        bf16x8 zz;
#pragma unroll
        for (int j = 0; j < 8; ++j) zz[j] = (__bf16)0.f;
#pragma unroll 1
        for (int nl = 0; nl < 16; ++nl) {
            __bf16* dst = base + ((nb + nl) * 256 + z) * 32;
            bf16x8 v0, v1 = zz;
            const float* gy = (which == 0) ? gy0s[nl] : gy1s[nl];
#pragma unroll
            for (int d = 0; d < 8; ++d) v0[d] = (__bf16)(gy[d] * wv[d]);
            v1[0] = (which == 0) ? c0b[nl][z] : c1b[nl][z];
            *(bf16x8*)(dst)      = v0;
            *(bf16x8*)(dst + 8)  = v1;
            *(bf16x8*)(dst + 16) = zz;
            *(bf16x8*)(dst + 24) = zz;
        }
    }
}

// ---------------------------------------------------------------------------
// k_main: exact round-2 structure (81 us measured): WTB via L2, padded zh.
// ---------------------------------------------------------------------------
__global__ __launch_bounds__(256, 3) void k_main(
    const float* __restrict__ U,
    float* __restrict__ ws)
{
    __shared__ __bf16 zh[64][264];   // +8 pad
    __shared__ float gz1s[256];
    __shared__ float w2s[256];
    __shared__ float sdot[64];
    __shared__ float psum[4][64];

    const int t  = threadIdx.x;
    const int n  = blockIdx.y;
    const int m0 = blockIdx.x * 64;
    const int w    = t >> 6;
    const int lane = t & 63;
    const int c = lane & 15;
    const int q = lane >> 4;

    gz1s[t] = ws[WS_GZ1 + n * 256 + t];
    w2s[t]  = ws[WS_W2  + n * 256 + t];
    if (t < 64) {
        float sd = 0.f;
#pragma unroll
        for (int d = 0; d < 8; ++d)
            sd += U[(m0 + t) * 8 + d] * ws[WS_YV + n * 8 + d];
        sdot[t] = sd;
    }

    const __bf16* A2p = (const __bf16*)(ws + WS_A2);
    const __bf16* B2p = (const __bf16*)(ws + WS_B2) + n * 8192;
    const __bf16* BXp = (const __bf16*)(ws + WS_BX) + n * 8192;
    const __bf16* WTp = (const __bf16*)(ws + WS_WTB);

    bf16x8 a2f[4];
#pragma unroll
    for (int mi = 0; mi < 4; ++mi)
        a2f[mi] = *(const bf16x8*)(A2p + (m0 + 16 * mi + c) * 32 + q * 8);

    // ---- pre-GEMM: D1[z][m], wave w covers z in [64w, 64w+64) ----
    {
        bf16x8 b2f[4];
#pragma unroll
        for (int zt = 0; zt < 4; ++zt)
            b2f[zt] = *(const bf16x8*)(B2p + (64 * w + 16 * zt + c) * 32 + q * 8);
        f32x4 pre[4][4];
#pragma unroll
        for (int zt = 0; zt < 4; ++zt)
#pragma unroll
            for (int mi = 0; mi < 4; ++mi) {
                f32x4 zacc = {0.f, 0.f, 0.f, 0.f};
                pre[zt][mi] = __builtin_amdgcn_mfma_f32_16x16x32_bf16(
                    b2f[zt], a2f[mi], zacc, 0, 0, 0);
            }
#pragma unroll
        for (int zt = 0; zt < 4; ++zt) {
            const int zb = 64 * w + 16 * zt + 4 * q;
#pragma unroll
            for (int mi = 0; mi < 4; ++mi) {
                bf16x4 v4;
#pragma unroll
                for (int r = 0; r < 4; ++r)
                    v4[r] = (__bf16)(fmaxf(pre[zt][mi][r], 0.f) * gz1s[zb + r]);
                *(bf16x4*)&zh[c + 16 * mi][zb] = v4;
            }
        }
    }

    // ---- main GEMM: D2[m][k], wave w covers k in [64w, 64w+64) ----
    f32x4 acc[4][4];
#pragma unroll
    for (int mi = 0; mi < 4; ++mi)
#pragma unroll
        for (int kj = 0; kj < 4; ++kj)
            acc[mi][kj] = f32x4{0.f, 0.f, 0.f, 0.f};

    __syncthreads();

    for (int ch = 0; ch < 8; ++ch) {
        bf16x8 az[4], bw[4];
#pragma unroll
        for (int mi = 0; mi < 4; ++mi)
            az[mi] = *(const bf16x8*)&zh[c + 16 * mi][ch * 32 + q * 8];
#pragma unroll
        for (int kj = 0; kj < 4; ++kj)
            bw[kj] = *(const bf16x8*)(WTp + (64 * w + 16 * kj + c) * 256 + ch * 32 + q * 8);
#pragma unroll
        for (int mi = 0; mi < 4; ++mi)
#pragma unroll
            for (int kj = 0; kj < 4; ++kj)
                acc[mi][kj] = __builtin_amdgcn_mfma_f32_16x16x32_bf16(
                    az[mi], bw[kj], acc[mi][kj], 0, 0, 0);
    }
    // rank-1 chunk: [U|1] x [gy1*Wy1 | c1]
    {
        bf16x8 bx[4];
#pragma unroll
        for (int kj = 0; kj < 4; ++kj)
            bx[kj] = *(const bf16x8*)(BXp + (64 * w + 16 * kj + c) * 32 + q * 8);
#pragma unroll
        for (int mi = 0; mi < 4; ++mi)
#pragma unroll
            for (int kj = 0; kj < 4; ++kj)
                acc[mi][kj] = __builtin_amdgcn_mfma_f32_16x16x32_bf16(
                    a2f[mi], bx[kj], acc[mi][kj], 0, 0, 0);
    }

    // ---- epilogue: p[m] = sum_k relu(acc)*w2[k] ----
    float p[4][4];
#pragma unroll
    for (int mi = 0; mi < 4; ++mi)
#pragma unroll
        for (int r = 0; r < 4; ++r) p[mi][r] = 0.f;
#pragma unroll
    for (int kj = 0; kj < 4; ++kj) {
        float w2v = w2s[64 * w + 16 * kj + c];
#pragma unroll
        for (int mi = 0; mi < 4; ++mi)
#pragma unroll
            for (int r = 0; r < 4; ++r)
                p[mi][r] += fmaxf(acc[mi][kj][r], 0.f) * w2v;
    }
#pragma unroll
    for (int mi = 0; mi < 4; ++mi)
#pragma unroll
        for (int r = 0; r < 4; ++r) {
            float v = p[mi][r];
            v += __shfl_xor(v, 8);
            v += __shfl_xor(v, 4);
            v += __shfl_xor(v, 2);
            v += __shfl_xor(v, 1);
            p[mi][r] = v;
        }
    if (c == 0) {
#pragma unroll
        for (int mi = 0; mi < 4; ++mi)
            *(float4*)&psum[w][16 * mi + 4 * q] =
                make_float4(p[mi][0], p[mi][1], p[mi][2], p[mi][3]);
    }
    __syncthreads();
    if (t < 64) {
        float cu2 = ws[WS_CU2 + n];
        float pp = psum[0][t] + psum[1][t] + psum[2][t] + psum[3][t];
        ws[WS_SLACK + n * 2048 + m0 + t] = sdot[t] - cu2 - pp;
    }
}

// ---------------------------------------------------------------------------
// k_lse: per-n stable logsumexp over m -> psi[n]
// ---------------------------------------------------------------------------
__global__ __launch_bounds__(256) void k_lse(const float* __restrict__ ws,
                                             float* __restrict__ out) {
    __shared__ float redmax[4];
    __shared__ float redsum[4];
    const int n = blockIdx.x;
    const int t = threadIdx.x;
    const float* s = ws + WS_SLACK + n * 2048;

    float vals[8];
    float mx = -3.4e38f;
#pragma unroll
    for (int i = 0; i < 8; ++i) {
        vals[i] = s[t + 256 * i];
        mx = fmaxf(mx, vals[i]);
    }
#pragma unroll
    for (int off = 32; off; off >>= 1) mx = fmaxf(mx, __shfl_xor(mx, off));
    if ((t & 63) == 0) redmax[t >> 6] = mx;
    __syncthreads();
    mx = fmaxf(fmaxf(redmax[0], redmax[1]), fmaxf(redmax[2], redmax[3]));

    float sum = 0.f;
#pragma unroll
    for (int i = 0; i < 8; ++i) sum += expf((vals[i] - mx) * (1.f / EPSF));
#pragma unroll
    for (int off = 32; off; off >>= 1) sum += __shfl_xor(sum, off);
    if ((t & 63) == 0) redsum[t >> 6] = sum;
    __syncthreads();
    if (t == 0) {
        float S = redsum[0] + redsum[1] + redsum[2] + redsum[3];
        out[n] = EPSF * logf(S * (1.f / 2048.f)) + mx;
    }
}

// ---------------------------------------------------------------------------
extern "C" void kernel_launch(void* const* d_in, const int* in_sizes, int n_in,
                              void* d_out, int out_size, void* d_ws, size_t ws_size,
                              hipStream_t stream) {
    const float* X    = (const float*)d_in[0];
    const float* Uu   = (const float*)d_in[1];
    const float* Yy   = (const float*)d_in[2];
    const float* Wt0  = (const float*)d_in[3];
    const float* bt0  = (const float*)d_in[4];
    const float* Wt1  = (const float*)d_in[5];
    const float* bt1  = (const float*)d_in[6];
    const float* Wyu0 = (const float*)d_in[7];
    const float* byu0 = (const float*)d_in[8];
    const float* Wy0  = (const float*)d_in[9];
    const float* Wu0  = (const float*)d_in[10];
    const float* b0   = (const float*)d_in[11];
    const float* Wzu1 = (const float*)d_in[12];
    const float* bzu1 = (const float*)d_in[13];
    const float* Wz1  = (const float*)d_in[14];
    const float* Wyu1 = (const float*)d_in[15];
    const float* byu1 = (const float*)d_in[16];
    const float* Wy1  = (const float*)d_in[17];
    const float* Wu1  = (const float*)d_in[18];
    const float* b1   = (const float*)d_in[19];
    const float* Wzu2 = (const float*)d_in[20];
    const float* bzu2 = (const float*)d_in[21];
    const float* Wz2  = (const float*)d_in[22];
    const float* Wyu2 = (const float*)d_in[23];
    const float* byu2 = (const float*)d_in[24];
    const float* Wy2  = (const float*)d_in[25];
    const float* Wu2  = (const float*)d_in[26];
    const float* b2   = (const float*)d_in[27];
    float* ws  = (float*)d_ws;
    float* out = (float*)d_out;

    k_prep<<<dim3(512), dim3(256), 0, stream>>>(Wz1, Uu, ws);
    k_ctx<<<dim3(8), dim3(512), 0, stream>>>(
        X, Yy, Wt0, bt0, Wt1, bt1, Wyu0, byu0, Wy0, Wu0, b0,
        Wzu1, bzu1, Wyu1, byu1, Wy1, Wu1, b1,
        Wzu2, bzu2, Wz2, Wyu2, byu2, Wy2, Wu2, b2, ws);
    k_main<<<dim3(MM / 64, NN), dim3(256), 0, stream>>>(Uu, ws);
    k_lse<<<dim3(128), dim3(256), 0, stream>>>(ws, out);
}

// Round 6
// 203.551 us; speedup vs baseline: 2.2634x; 1.1693x over previous
//
#include <hip/hip_runtime.h>

// Problem dims
#define NN 128
#define MM 2048
#define EPSF 0.01f

typedef __bf16 bf16x8 __attribute__((ext_vector_type(8)));
typedef __bf16 bf16x4 __attribute__((ext_vector_type(4)));
typedef float  f32x4  __attribute__((ext_vector_type(4)));

// Workspace layout (float offsets), total 1510528 floats = 6.04 MB
#define WS_SLACK 0            // [n][m] fp32
#define WS_W2    262144       // [n][256] fp32 gz2*softplus(Wz2)
#define WS_GZ1   294912       // [n][256] fp32
#define WS_YV    327680       // [n][8]  fp32 Y - gy2*Wy2
#define WS_CU2   328704       // [n]     fp32
#define WS_WTB   328832       // bf16 [256 k][256 z] = softplus(Wz1)
#define WS_A2    361600       // bf16 [2048 m][32] = [U | 1 | 0...]
#define WS_B2    394368       // bf16 [128 n][256 z][32] = [gy0*Wy0 | c0 | 0...]
#define WS_BX    918656       // bf16 [128 n][256 k][32] = [gy1*Wy1 | c1 | 0...]
#define WS_U1    1442944      // bf16 [128 n][256]
#define WS_U2    1459328      // bf16 [128 n][256]
#define WS_C0    1475712      // bf16 [128 n][256]
#define WS_C1    1492096      // bf16 [128 n][256]
#define WS_GY0   1508480      // fp32 [128 n][8]
#define WS_GY1   1509504      // fp32 [128 n][8]

__device__ __forceinline__ float softplusf(float x) {
    return x > 20.f ? x : log1pf(expf(x));
}

__device__ __forceinline__ bf16x8 ld_cvt8(const float* __restrict__ p) {
    const float4* p4 = (const float4*)p;
    float4 a = p4[0], b = p4[1];
    bf16x8 r;
    r[0] = (__bf16)a.x; r[1] = (__bf16)a.y; r[2] = (__bf16)a.z; r[3] = (__bf16)a.w;
    r[4] = (__bf16)b.x; r[5] = (__bf16)b.y; r[6] = (__bf16)b.z; r[7] = (__bf16)b.w;
    return r;
}

// ---------------------------------------------------------------------------
// Context level kernels: wide grids, one 16-col x 16-n MFMA tile per wave.
// D = mfma(aF, bF): row(4q+r) = n-local, col(c) = output col.
// ---------------------------------------------------------------------------

// Level 1: K=64 over X. 33 col-tiles: [0,16)=Wt0->u1, [16,32)=Wu0->c0, 32=Wyu0->gy0
__global__ __launch_bounds__(256) void k_l1(
    const float* __restrict__ X,
    const float* __restrict__ Wt0, const float* __restrict__ bt0,
    const float* __restrict__ Wu0, const float* __restrict__ b0,
    const float* __restrict__ Wyu0, const float* __restrict__ byu0,
    float* __restrict__ ws)
{
    const int t = threadIdx.x, w = t >> 6, lane = t & 63;
    const int c = lane & 15, q = lane >> 4;
    const int nb = blockIdx.y * 16;
    const int ct = blockIdx.x * 4 + w;
    if (ct >= 33) return;

    bf16x8 a1[2];
#pragma unroll
    for (int ch = 0; ch < 2; ++ch)
        a1[ch] = ld_cvt8(X + (nb + c) * 64 + ch * 32 + q * 8);

    const float* rp;
    int col;
    if (ct < 16)      { col = ct * 16 + c;        rp = Wt0 + col * 64; }
    else if (ct < 32) { col = (ct - 16) * 16 + c; rp = Wu0 + col * 64; }
    else              { col = c & 7;              rp = Wyu0 + col * 64; }

    f32x4 D = {0.f, 0.f, 0.f, 0.f};
#pragma unroll
    for (int ch = 0; ch < 2; ++ch) {
        bf16x8 b = ld_cvt8(rp + ch * 32 + q * 8);
        D = __builtin_amdgcn_mfma_f32_16x16x32_bf16(a1[ch], b, D, 0, 0, 0);
    }

    if (ct < 16) {
        __bf16* u1p = (__bf16*)(ws + WS_U1);
        const float bv = bt0[col];
#pragma unroll
        for (int r = 0; r < 4; ++r)
            u1p[(nb + 4 * q + r) * 256 + col] = (__bf16)fmaxf(D[r] + bv, 0.f);
    } else if (ct < 32) {
        __bf16* c0p = (__bf16*)(ws + WS_C0);
        const float bv = b0[col];
#pragma unroll
        for (int r = 0; r < 4; ++r)
            c0p[(nb + 4 * q + r) * 256 + col] = (__bf16)(D[r] + bv);
    } else if (c < 8) {
        const float bv = byu0[c];
#pragma unroll
        for (int r = 0; r < 4; ++r)
            ws[WS_GY0 + (nb + 4 * q + r) * 8 + c] = D[r] + bv;
    }
}

// Level 2: K=256 over u1 (bf16). 49 tiles: Wt1->u2 | Wzu1->gz1 | Wu1->c1 | Wyu1->gy1
__global__ __launch_bounds__(256) void k_l2(
    const float* __restrict__ Wt1, const float* __restrict__ bt1,
    const float* __restrict__ Wzu1, const float* __restrict__ bzu1,
    const float* __restrict__ Wu1, const float* __restrict__ b1,
    const float* __restrict__ Wyu1, const float* __restrict__ byu1,
    float* __restrict__ ws)
{
    const int t = threadIdx.x, w = t >> 6, lane = t & 63;
    const int c = lane & 15, q = lane >> 4;
    const int nb = blockIdx.y * 16;
    const int ct = blockIdx.x * 4 + w;
    if (ct >= 49) return;

    const __bf16* u1p = (const __bf16*)(ws + WS_U1);
    bf16x8 aF[8];
#pragma unroll
    for (int ch = 0; ch < 8; ++ch)
        aF[ch] = *(const bf16x8*)(u1p + (nb + c) * 256 + ch * 32 + q * 8);

    const float* rp;
    int col;
    if (ct < 16)      { col = ct * 16 + c;        rp = Wt1 + col * 256; }
    else if (ct < 32) { col = (ct - 16) * 16 + c; rp = Wzu1 + col * 256; }
    else if (ct < 48) { col = (ct - 32) * 16 + c; rp = Wu1 + col * 256; }
    else              { col = c & 7;              rp = Wyu1 + col * 256; }

    f32x4 D = {0.f, 0.f, 0.f, 0.f};
#pragma unroll
    for (int ch = 0; ch < 8; ++ch) {
        bf16x8 b = ld_cvt8(rp + ch * 32 + q * 8);
        D = __builtin_amdgcn_mfma_f32_16x16x32_bf16(aF[ch], b, D, 0, 0, 0);
    }

    if (ct < 16) {
        __bf16* u2p = (__bf16*)(ws + WS_U2);
        const float bv = bt1[col];
#pragma unroll
        for (int r = 0; r < 4; ++r)
            u2p[(nb + 4 * q + r) * 256 + col] = (__bf16)fmaxf(D[r] + bv, 0.f);
    } else if (ct < 32) {
        const float bv = bzu1[col];
#pragma unroll
        for (int r = 0; r < 4; ++r)
            ws[WS_GZ1 + (nb + 4 * q + r) * 256 + col] = fmaxf(D[r] + bv, 0.f);
    } else if (ct < 48) {
        __bf16* c1p = (__bf16*)(ws + WS_C1);
        const float bv = b1[col];
#pragma unroll
        for (int r = 0; r < 4; ++r)
            c1p[(nb + 4 * q + r) * 256 + col] = (__bf16)(D[r] + bv);
    } else if (c < 8) {
        const float bv = byu1[c];
#pragma unroll
        for (int r = 0; r < 4; ++r)
            ws[WS_GY1 + (nb + 4 * q + r) * 8 + c] = D[r] + bv;
    }
}

// Level 3: K=256 over u2 (bf16). 17 tiles: Wzu2->w2 | (Wyu2->yv, Wu2->cu2)
__global__ __launch_bounds__(256) void k_l3(
    const float* __restrict__ Y,
    const float* __restrict__ Wzu2, const float* __restrict__ bzu2,
    const float* __restrict__ Wz2,
    const float* __restrict__ Wyu2, const float* __restrict__ byu2,
    const float* __restrict__ Wy2,
    const float* __restrict__ Wu2, const float* __restrict__ b2,
    float* __restrict__ ws)
{
    const int t = threadIdx.x, w = t >> 6, lane = t & 63;
    const int c = lane & 15, q = lane >> 4;
    const int nb = blockIdx.y * 16;
    const int ct = blockIdx.x * 4 + w;
    if (ct >= 17) return;

    const __bf16* u2p = (const __bf16*)(ws + WS_U2);
    bf16x8 aF[8];
#pragma unroll
    for (int ch = 0; ch < 8; ++ch)
        aF[ch] = *(const bf16x8*)(u2p + (nb + c) * 256 + ch * 32 + q * 8);

    const float* rp;
    int col = 0;
    if (ct < 16) { col = ct * 16 + c; rp = Wzu2 + col * 256; }
    else         { rp = (c < 8) ? (Wyu2 + c * 256) : Wu2; }

    f32x4 D = {0.f, 0.f, 0.f, 0.f};
#pragma unroll
    for (int ch = 0; ch < 8; ++ch) {
        bf16x8 b = ld_cvt8(rp + ch * 32 + q * 8);
        D = __builtin_amdgcn_mfma_f32_16x16x32_bf16(aF[ch], b, D, 0, 0, 0);
    }

    if (ct < 16) {
        const float bv = bzu2[col];
        const float sp = softplusf(Wz2[col]);
#pragma unroll
        for (int r = 0; r < 4; ++r) {
            float gz2 = fmaxf(D[r] + bv, 0.f);
            ws[WS_W2 + (nb + 4 * q + r) * 256 + col] = gz2 * sp;
        }
    } else if (c < 8) {
        const float bv = byu2[c];
        const float wy2 = Wy2[c];
#pragma unroll
        for (int r = 0; r < 4; ++r) {
            const int n = nb + 4 * q + r;
            ws[WS_YV + n * 8 + c] = Y[n * 8 + c] - (D[r] + bv) * wy2;
        }
    } else if (c == 8) {
#pragma unroll
        for (int r = 0; r < 4; ++r)
            ws[WS_CU2 + nb + 4 * q + r] = D[r] + b2[0];
    }
}

// k_bmat: WTB cvt + A2 build + B2/BX row materialization. 256 blocks x 256.
__global__ __launch_bounds__(256) void k_bmat(
    const float* __restrict__ Wz1, const float* __restrict__ U,
    const float* __restrict__ Wy0, const float* __restrict__ Wy1,
    float* __restrict__ ws)
{
    const int b = blockIdx.x, t = threadIdx.x;
    const int i = b * 256 + t;

    ((__bf16*)(ws + WS_WTB))[i] = (__bf16)softplusf(Wz1[i]);
    {
        int m = i >> 5, cc = i & 31;
        float v = cc < 8 ? U[m * 8 + cc] : (cc == 8 ? 1.f : 0.f);
        ((__bf16*)(ws + WS_A2))[i] = (__bf16)v;
    }

    const int which = b >> 7, n = b & 127, z = t;
    const float* wy = (which ? Wy1 : Wy0) + z * 8;
    const float* gy = ws + (which ? WS_GY1 : WS_GY0) + n * 8;
    const __bf16* cp = (const __bf16*)(ws + (which ? WS_C1 : WS_C0)) + n * 256 + z;
    __bf16* dst = (__bf16*)(ws + (which ? WS_BX : WS_B2)) + (n * 256 + z) * 32;

    bf16x8 zz;
#pragma unroll
    for (int j = 0; j < 8; ++j) zz[j] = (__bf16)0.f;
    bf16x8 v0, v1 = zz;
#pragma unroll
    for (int d = 0; d < 8; ++d) v0[d] = (__bf16)(gy[d] * wy[d]);
    v1[0] = *cp;
    *(bf16x8*)(dst)      = v0;
    *(bf16x8*)(dst + 8)  = v1;
    *(bf16x8*)(dst + 16) = zz;
    *(bf16x8*)(dst + 24) = zz;
}

// ---------------------------------------------------------------------------
// k_main: round-2 structure, occupancy 3 -> 4 blocks/CU.
// ---------------------------------------------------------------------------
__global__ __launch_bounds__(256, 4) void k_main(
    const float* __restrict__ U,
    float* __restrict__ ws)
{
    __shared__ __bf16 zh[64][264];   // +8 pad
    __shared__ float gz1s[256];
    __shared__ float w2s[256];
    __shared__ float sdot[64];
    __shared__ float psum[4][64];

    const int t  = threadIdx.x;
    const int n  = blockIdx.y;
    const int m0 = blockIdx.x * 64;
    const int w    = t >> 6;
    const int lane = t & 63;
    const int c = lane & 15;
    const int q = lane >> 4;

    gz1s[t] = ws[WS_GZ1 + n * 256 + t];
    w2s[t]  = ws[WS_W2  + n * 256 + t];
    if (t < 64) {
        float sd = 0.f;
#pragma unroll
        for (int d = 0; d < 8; ++d)
            sd += U[(m0 + t) * 8 + d] * ws[WS_YV + n * 8 + d];
        sdot[t] = sd;
    }

    const __bf16* A2p = (const __bf16*)(ws + WS_A2);
    const __bf16* B2p = (const __bf16*)(ws + WS_B2) + n * 8192;
    const __bf16* BXp = (const __bf16*)(ws + WS_BX) + n * 8192;
    const __bf16* WTp = (const __bf16*)(ws + WS_WTB);

    bf16x8 a2f[4];
#pragma unroll
    for (int mi = 0; mi < 4; ++mi)
        a2f[mi] = *(const bf16x8*)(A2p + (m0 + 16 * mi + c) * 32 + q * 8);

    // ---- pre-GEMM: D1[z][m], wave w covers z in [64w, 64w+64) ----
    {
        bf16x8 b2f[4];
#pragma unroll
        for (int zt = 0; zt < 4; ++zt)
            b2f[zt] = *(const bf16x8*)(B2p + (64 * w + 16 * zt + c) * 32 + q * 8);
        f32x4 pre[4][4];
#pragma unroll
        for (int zt = 0; zt < 4; ++zt)
#pragma unroll
            for (int mi = 0; mi < 4; ++mi) {
                f32x4 zacc = {0.f, 0.f, 0.f, 0.f};
                pre[zt][mi] = __builtin_amdgcn_mfma_f32_16x16x32_bf16(
                    b2f[zt], a2f[mi], zacc, 0, 0, 0);
            }
#pragma unroll
        for (int zt = 0; zt < 4; ++zt) {
            const int zb = 64 * w + 16 * zt + 4 * q;
#pragma unroll
            for (int mi = 0; mi < 4; ++mi) {
                bf16x4 v4;
#pragma unroll
                for (int r = 0; r < 4; ++r)
                    v4[r] = (__bf16)(fmaxf(pre[zt][mi][r], 0.f) * gz1s[zb + r]);
                *(bf16x4*)&zh[c + 16 * mi][zb] = v4;
            }
        }
    }

    // ---- main GEMM: D2[m][k], wave w covers k in [64w, 64w+64) ----
    f32x4 acc[4][4];
#pragma unroll
    for (int mi = 0; mi < 4; ++mi)
#pragma unroll
        for (int kj = 0; kj < 4; ++kj)
            acc[mi][kj] = f32x4{0.f, 0.f, 0.f, 0.f};

    __syncthreads();

    for (int ch = 0; ch < 8; ++ch) {
        bf16x8 az[4], bw[4];
#pragma unroll
        for (int mi = 0; mi < 4; ++mi)
            az[mi] = *(const bf16x8*)&zh[c + 16 * mi][ch * 32 + q * 8];
#pragma unroll
        for (int kj = 0; kj < 4; ++kj)
            bw[kj] = *(const bf16x8*)(WTp + (64 * w + 16 * kj + c) * 256 + ch * 32 + q * 8);
#pragma unroll
        for (int mi = 0; mi < 4; ++mi)
#pragma unroll
            for (int kj = 0; kj < 4; ++kj)
                acc[mi][kj] = __builtin_amdgcn_mfma_f32_16x16x32_bf16(
                    az[mi], bw[kj], acc[mi][kj], 0, 0, 0);
    }
    // rank-1 chunk: [U|1] x [gy1*Wy1 | c1]
    {
        bf16x8 bx[4];
#pragma unroll
        for (int kj = 0; kj < 4; ++kj)
            bx[kj] = *(const bf16x8*)(BXp + (64 * w + 16 * kj + c) * 32 + q * 8);
#pragma unroll
        for (int mi = 0; mi < 4; ++mi)
#pragma unroll
            for (int kj = 0; kj < 4; ++kj)
                acc[mi][kj] = __builtin_amdgcn_mfma_f32_16x16x32_bf16(
                    a2f[mi], bx[kj], acc[mi][kj], 0, 0, 0);
    }

    // ---- epilogue: p[m] = sum_k relu(acc)*w2[k] ----
    float p[4][4];
#pragma unroll
    for (int mi = 0; mi < 4; ++mi)
#pragma unroll
        for (int r = 0; r < 4; ++r) p[mi][r] = 0.f;
#pragma unroll
    for (int kj = 0; kj < 4; ++kj) {
        float w2v = w2s[64 * w + 16 * kj + c];
#pragma unroll
        for (int mi = 0; mi < 4; ++mi)
#pragma unroll
            for (int r = 0; r < 4; ++r)
                p[mi][r] += fmaxf(acc[mi][kj][r], 0.f) * w2v;
    }
#pragma unroll
    for (int mi = 0; mi < 4; ++mi)
#pragma unroll
        for (int r = 0; r < 4; ++r) {
            float v = p[mi][r];
            v += __shfl_xor(v, 8);
            v += __shfl_xor(v, 4);
            v += __shfl_xor(v, 2);
            v += __shfl_xor(v, 1);
            p[mi][r] = v;
        }
    if (c == 0) {
#pragma unroll
        for (int mi = 0; mi < 4; ++mi)
            *(float4*)&psum[w][16 * mi + 4 * q] =
                make_float4(p[mi][0], p[mi][1], p[mi][2], p[mi][3]);
    }
    __syncthreads();
    if (t < 64) {
        float cu2 = ws[WS_CU2 + n];
        float pp = psum[0][t] + psum[1][t] + psum[2][t] + psum[3][t];
        ws[WS_SLACK + n * 2048 + m0 + t] = sdot[t] - cu2 - pp;
    }
}

// ---------------------------------------------------------------------------
// k_lse: per-n stable logsumexp over m -> psi[n]
// ---------------------------------------------------------------------------
__global__ __launch_bounds__(256) void k_lse(const float* __restrict__ ws,
                                             float* __restrict__ out) {
    __shared__ float redmax[4];
    __shared__ float redsum[4];
    const int n = blockIdx.x;
    const int t = threadIdx.x;
    const float* s = ws + WS_SLACK + n * 2048;

    float vals[8];
    float mx = -3.4e38f;
#pragma unroll
    for (int i = 0; i < 8; ++i) {
        vals[i] = s[t + 256 * i];
        mx = fmaxf(mx, vals[i]);
    }
#pragma unroll
    for (int off = 32; off; off >>= 1) mx = fmaxf(mx, __shfl_xor(mx, off));
    if ((t & 63) == 0) redmax[t >> 6] = mx;
    __syncthreads();
    mx = fmaxf(fmaxf(redmax[0], redmax[1]), fmaxf(redmax[2], redmax[3]));

    float sum = 0.f;
#pragma unroll
    for (int i = 0; i < 8; ++i) sum += expf((vals[i] - mx) * (1.f / EPSF));
#pragma unroll
    for (int off = 32; off; off >>= 1) sum += __shfl_xor(sum, off);
    if ((t & 63) == 0) redsum[t >> 6] = sum;
    __syncthreads();
    if (t == 0) {
        float S = redsum[0] + redsum[1] + redsum[2] + redsum[3];
        out[n] = EPSF * logf(S * (1.f / 2048.f)) + mx;
    }
}

// ---------------------------------------------------------------------------
extern "C" void kernel_launch(void* const* d_in, const int* in_sizes, int n_in,
                              void* d_out, int out_size, void* d_ws, size_t ws_size,
                              hipStream_t stream) {
    const float* X    = (const float*)d_in[0];
    const float* Uu   = (const float*)d_in[1];
    const float* Yy   = (const float*)d_in[2];
    const float* Wt0  = (const float*)d_in[3];
    const float* bt0  = (const float*)d_in[4];
    const float* Wt1  = (const float*)d_in[5];
    const float* bt1  = (const float*)d_in[6];
    const float* Wyu0 = (const float*)d_in[7];
    const float* byu0 = (const float*)d_in[8];
    const float* Wy0  = (const float*)d_in[9];
    const float* Wu0  = (const float*)d_in[10];
    const float* b0   = (const float*)d_in[11];
    const float* Wzu1 = (const float*)d_in[12];
    const float* bzu1 = (const float*)d_in[13];
    const float* Wz1  = (const float*)d_in[14];
    const float* Wyu1 = (const float*)d_in[15];
    const float* byu1 = (const float*)d_in[16];
    const float* Wy1  = (const float*)d_in[17];
    const float* Wu1  = (const float*)d_in[18];
    const float* b1   = (const float*)d_in[19];
    const float* Wzu2 = (const float*)d_in[20];
    const float* bzu2 = (const float*)d_in[21];
    const float* Wz2  = (const float*)d_in[22];
    const float* Wyu2 = (const float*)d_in[23];
    const float* byu2 = (const float*)d_in[24];
    const float* Wy2  = (const float*)d_in[25];
    const float* Wu2  = (const float*)d_in[26];
    const float* b2   = (const float*)d_in[27];
    float* ws  = (float*)d_ws;
    float* out = (float*)d_out;

    k_l1<<<dim3(9, 8),  dim3(256), 0, stream>>>(X, Wt0, bt0, Wu0, b0, Wyu0, byu0, ws);
    k_l2<<<dim3(13, 8), dim3(256), 0, stream>>>(Wt1, bt1, Wzu1, bzu1, Wu1, b1, Wyu1, byu1, ws);
    k_l3<<<dim3(5, 8),  dim3(256), 0, stream>>>(Yy, Wzu2, bzu2, Wz2, Wyu2, byu2, Wy2, Wu2, b2, ws);
    k_bmat<<<dim3(256), dim3(256), 0, stream>>>(Wz1, Uu, Wy0, Wy1, ws);
    k_main<<<dim3(MM / 64, NN), dim3(256), 0, stream>>>(Uu, ws);
    k_lse<<<dim3(128), dim3(256), 0, stream>>>(ws, out);
}